// Round 7
// baseline (80.538 us; speedup 1.0000x reference)
//
#include <hip/hip_runtime.h>

typedef __attribute__((ext_vector_type(8))) short short8;
typedef __attribute__((ext_vector_type(4))) float f32x4;

__device__ __forceinline__ unsigned short f2bf(float f) {
    union { float f; unsigned int u; } v; v.f = f;
    unsigned int u = v.u;
    unsigned int r = u + 0x7FFFu + ((u >> 16) & 1u);
    return (unsigned short)(r >> 16);
}

// Kernel A: IDENTICAL to R3 (anchor).
__global__ __launch_bounds__(1024) void wmat_kernel(
    const float* __restrict__ v_w, const float* __restrict__ proj_w,
    unsigned short* __restrict__ Wm)
{
    __shared__ float red[4][256];
    const int e  = blockIdx.x;
    const int c  = threadIdx.x & 255;
    const int dq = threadIdx.x >> 8;   // 0..3

    const float* pw = proj_w + e * 256 + dq * 64;   // wave-uniform -> s_loads
    const float* vv = v_w + (dq * 64) * 256 + c;

    float acc = 0.f;
#pragma unroll 8
    for (int d = 0; d < 64; ++d)
        acc = fmaf(pw[d], vv[d * 256], acc);

    red[dq][c] = acc;
    __syncthreads();
    if (threadIdx.x < 256) {
        float s = red[0][c] + red[1][c] + red[2][c] + red[3][c];
        Wm[e * 256 + c] = f2bf(s);
    }
}

// Kernel B: R3's fused kernel with the body repeated TWICE (idempotent,
// deterministic -> harness-legal). Purpose: push this dispatch to ~49us so it
// beats the ~41us harness fill kernels into the rocprof top-5 and we finally
// see OccupancyPercent / VALUBusy / MfmaUtil / FETCH_SIZE / bank conflicts.
// dur_total - R3_total also gives the warm-cache marginal cost of the body.
__global__ __launch_bounds__(256, 4) void fused_kernel(
    const float* __restrict__ x, const unsigned short* __restrict__ Wm,
    const float* __restrict__ proj_b, float* __restrict__ out)
{
    const int idx   = ((blockIdx.x & 7) << 7) | (blockIdx.x >> 3);  // 1024 = 8*128, bijective
    const int b     = idx >> 7;
    const int h     = (idx >> 1) & 63;
    const int wbase = (idx & 1) * 32;
    const int t     = threadIdx.x;

    __shared__ unsigned short ylds[32 * 256];   // 16 KB, bf16, XOR-swizzled

    const float A1  = (float)(1.0 / 10.71828182845904523536);                 // 1/(e+8)
    const float A0D = (float)(2.71828182845904523536 / 10.71828182845904523536) - A1; // A0-A1

    for (int rep = 0; rep < 2; ++rep) {
        asm volatile("" ::: "memory");   // block cross-rep CSE of x loads (rule #17)

        // ---------------- blur phase (4-pixel strip per thread) ----------------
        {
            const int wl0 = (t >> 5) * 4;     // local strip start in [0,32)
            const int c0  = (t & 31) * 8;     // 8-channel chunk
            const int gw0 = wbase + wl0;      // global pixel of strip start

            const f32x4 z = {0.f, 0.f, 0.f, 0.f};
            f32x4 acc[4][2];
#pragma unroll
            for (int i = 0; i < 4; ++i) { acc[i][0] = z; acc[i][1] = z; }

            for (int r = h - 1; r <= h + 1; ++r) {
                if (r < 0 || r >= 64) continue;
                const bool top = (r == h - 1);
                const float* xr = x + (((size_t)b * 64 + r) * 64) * 256 + c0;

                f32x4 pm0, pm1, pc0, pc1;
                if (gw0 == 0) { pm0 = z; pm1 = z; }
                else {
                    pm0 = *(const f32x4*)(xr + (gw0 - 1) * 256);
                    pm1 = *(const f32x4*)(xr + (gw0 - 1) * 256 + 4);
                }
                pc0 = *(const f32x4*)(xr + gw0 * 256);
                pc1 = *(const f32x4*)(xr + gw0 * 256 + 4);

#pragma unroll
                for (int i = 0; i < 4; ++i) {
                    const int gwn = gw0 + i + 1;
                    f32x4 pn0 = z, pn1 = z;
                    if (gwn < 64) {
                        pn0 = *(const f32x4*)(xr + gwn * 256);
                        pn1 = *(const f32x4*)(xr + gwn * 256 + 4);
                    }
                    f32x4 s0 = pm0 + pc0 + pn0;
                    f32x4 s1 = pm1 + pc1 + pn1;
                    acc[i][0] += A1 * s0;
                    acc[i][1] += A1 * s1;
                    if (top) {   // tap k=0 extra weight on x[h-1][w-1]
                        acc[i][0] += A0D * pm0;
                        acc[i][1] += A0D * pm1;
                    }
                    pm0 = pc0; pm1 = pc1; pc0 = pn0; pc1 = pn1;
                }
            }

            // pack to bf16, write swizzled: byte ^= ((w&7)<<4)
#pragma unroll
            for (int i = 0; i < 4; ++i) {
                const int w = wl0 + i;        // local row in [0,32)
                union { short8 v; unsigned short u[8]; } pk;
#pragma unroll
                for (int j = 0; j < 4; ++j) {
                    pk.u[j]     = f2bf(acc[i][0][j]);
                    pk.u[4 + j] = f2bf(acc[i][1][j]);
                }
                unsigned baddr = ((unsigned)w * 512u + (unsigned)c0 * 2u) ^ (((unsigned)(w & 7)) << 4);
                *reinterpret_cast<short8*>(reinterpret_cast<char*>(ylds) + baddr) = pk.v;
            }
        }
        __syncthreads();

        // ---------------- GEMM phase: out[32,256] = y @ Wm^T + b ----------------
        {
            const int wave = t >> 6;          // 0..3 -> N quarter [wave*64, +64)
            const int lane = t & 63;
            const int lrow = lane & 15;
            const int lkg  = lane >> 4;       // 0..3 k-group
            const int n_base = wave * 64;

            const f32x4 z = {0.f, 0.f, 0.f, 0.f};
            f32x4 acc2[2][4];                 // [mi(pixel block)][ni(e block)]
#pragma unroll
            for (int mi = 0; mi < 2; ++mi)
#pragma unroll
                for (int ni = 0; ni < 4; ++ni) acc2[mi][ni] = z;

            for (int k0 = 0; k0 < 256; k0 += 32) {
                const int koff = k0 + lkg * 8;
                short8 a[2], bf[4];
#pragma unroll
                for (int mi = 0; mi < 2; ++mi) {
                    const int row = mi * 16 + lrow;
                    unsigned baddr = ((unsigned)row * 512u + (unsigned)koff * 2u) ^ (((unsigned)(row & 7)) << 4);
                    a[mi] = *reinterpret_cast<const short8*>(reinterpret_cast<const char*>(ylds) + baddr);
                }
#pragma unroll
                for (int ni = 0; ni < 4; ++ni) {
                    const int e = n_base + ni * 16 + lrow;
                    bf[ni] = *reinterpret_cast<const short8*>(Wm + e * 256 + koff);
                }
#pragma unroll
                for (int mi = 0; mi < 2; ++mi)
#pragma unroll
                    for (int ni = 0; ni < 4; ++ni)
                        acc2[mi][ni] = __builtin_amdgcn_mfma_f32_16x16x32_bf16(bf[ni], a[mi], acc2[mi][ni], 0, 0, 0);
            }

            // epilogue: vector bias + f32x4 nontemporal stores
            const size_t outbase = (((size_t)b * 64 + h) * 64 + wbase) * 256;
            f32x4 bias4[4];
#pragma unroll
            for (int ni = 0; ni < 4; ++ni)
                bias4[ni] = *reinterpret_cast<const f32x4*>(proj_b + n_base + ni * 16 + lkg * 4);

#pragma unroll
            for (int mi = 0; mi < 2; ++mi) {
                const int pixel = mi * 16 + lrow;   // local pixel in [0,32)
                float* orow = out + outbase + (size_t)pixel * 256 + n_base + lkg * 4;
#pragma unroll
                for (int ni = 0; ni < 4; ++ni) {
                    f32x4 v = acc2[mi][ni] + bias4[ni];
                    __builtin_nontemporal_store(v, reinterpret_cast<f32x4*>(orow + ni * 16));
                }
            }
        }
        __syncthreads();   // protect ylds before next rep's blur overwrites it
    }
}

extern "C" void kernel_launch(void* const* d_in, const int* in_sizes, int n_in,
                              void* d_out, int out_size, void* d_ws, size_t ws_size,
                              hipStream_t stream) {
    const float* x      = (const float*)d_in[0];
    const float* v_w    = (const float*)d_in[1];
    const float* proj_w = (const float*)d_in[2];
    const float* proj_b = (const float*)d_in[3];
    float* out = (float*)d_out;
    unsigned short* Wm = (unsigned short*)d_ws;   // 256*256 bf16 = 128 KB

    wmat_kernel<<<256, 1024, 0, stream>>>(v_w, proj_w, Wm);
    fused_kernel<<<1024, 256, 0, stream>>>(x, Wm, proj_b, out);
}

// Round 8
// 29.839 us; speedup vs baseline: 2.6991x; 2.6991x over previous
//
#include <hip/hip_runtime.h>

typedef __attribute__((ext_vector_type(8))) short short8;
typedef __attribute__((ext_vector_type(4))) float f32x4;

__device__ __forceinline__ unsigned short f2bf(float f) {
    union { float f; unsigned int u; } v; v.f = f;
    unsigned int u = v.u;
    unsigned int r = u + 0x7FFFu + ((u >> 16) & 1u);
    return (unsigned short)(r >> 16);
}

// Kernel A: W = proj_w @ v_w, bf16, stored PRE-SWIZZLED (R6-verified layout):
// element W[e][c], e=(wn*64+ni*16+lrow), c=(kk*32+lkg*8+c8), lane=lkg*16+lrow
// -> idx = (((wn*8+kk)*4+ni)*64 + lane)*8 + c8. GEMM B-loads become contiguous
// 1KB wave-loads.
__global__ __launch_bounds__(1024) void wmat_kernel(
    const float* __restrict__ v_w, const float* __restrict__ proj_w,
    unsigned short* __restrict__ Wm)
{
    __shared__ float red[4][256];
    const int e  = blockIdx.x;
    const int c  = threadIdx.x & 255;
    const int dq = threadIdx.x >> 8;   // 0..3

    const float* pw = proj_w + e * 256 + dq * 64;   // wave-uniform -> s_loads
    const float* vv = v_w + (dq * 64) * 256 + c;

    float acc = 0.f;
#pragma unroll 8
    for (int d = 0; d < 64; ++d)
        acc = fmaf(pw[d], vv[d * 256], acc);

    red[dq][c] = acc;
    __syncthreads();
    if (threadIdx.x < 256) {
        float s = red[0][c] + red[1][c] + red[2][c] + red[3][c];
        const int wn = e >> 6, ni = (e >> 4) & 3, lrow = e & 15;
        const int kk = c >> 5, lkg = (c >> 3) & 3, c8 = c & 7;
        const int lane = lkg * 16 + lrow;
        const int idxo = ((((wn * 8 + kk) * 4 + ni) * 64 + lane) * 8) + c8;
        Wm[idxo] = f2bf(s);
    }
}

// Kernel B: one block per 16-px quarter-row. 2048 blocks x 256 thr, 16KB LDS,
// launch_bounds(256,8) -> 8 blocks/CU = 32 waves/CU (occupancy 39% -> ~100%).
// Phase 1: blur -> bf16 in XOR-swizzled LDS (2-px strip/thread).
// Phase 2: wave wn owns 64-e quarter; A from LDS, B = contiguous 1KB loads from
//          pre-swizzled Wm; operand-swapped MFMA (R3/R6-verified D layout).
// Phase 3: transpose acc through f32 LDS tile -> each store = 1KB contiguous
//          full-line row write (kills the 2x write amplification seen in R7).
__global__ __launch_bounds__(256, 8) void fused_kernel(
    const float* __restrict__ x, const unsigned short* __restrict__ Wm,
    const float* __restrict__ proj_b, float* __restrict__ out)
{
    const int idx   = ((blockIdx.x & 7) << 8) | (blockIdx.x >> 3);  // 2048=8*256, bijective
    const int b     = idx >> 8;
    const int h     = (idx >> 2) & 63;
    const int wbase = (idx & 3) * 16;
    const int t     = threadIdx.x;

    __shared__ char ldsraw[16 * 256 * 4];   // 16 KB: bf16 y-tile, then f32 out-tile

    const float A1  = (float)(1.0 / 10.71828182845904523536);                 // 1/(e+8)
    const float A0D = (float)(2.71828182845904523536 / 10.71828182845904523536) - A1; // A0-A1

    // ---------------- blur: 8 strips(2px) x 32 chunks(8ch) ----------------
    {
        const int strip = t >> 5;         // 0..7
        const int c0    = (t & 31) * 8;   // 8-channel chunk
        const int px0   = strip * 2;      // local pixel in [0,16)
        const int gw0   = wbase + px0;    // global pixel column

        const f32x4 z = {0.f, 0.f, 0.f, 0.f};
        f32x4 acc[2][2];
#pragma unroll
        for (int i = 0; i < 2; ++i) { acc[i][0] = z; acc[i][1] = z; }

        for (int r = h - 1; r <= h + 1; ++r) {
            if (r < 0 || r >= 64) continue;
            const bool top = (r == h - 1);
            const float* xr = x + (((size_t)b * 64 + r) * 64) * 256 + c0;

            f32x4 pm0, pm1, pc0, pc1;
            if (gw0 == 0) { pm0 = z; pm1 = z; }
            else {
                pm0 = *(const f32x4*)(xr + (gw0 - 1) * 256);
                pm1 = *(const f32x4*)(xr + (gw0 - 1) * 256 + 4);
            }
            pc0 = *(const f32x4*)(xr + gw0 * 256);
            pc1 = *(const f32x4*)(xr + gw0 * 256 + 4);

#pragma unroll
            for (int i = 0; i < 2; ++i) {
                const int gwn = gw0 + i + 1;
                f32x4 pn0 = z, pn1 = z;
                if (gwn < 64) {
                    pn0 = *(const f32x4*)(xr + gwn * 256);
                    pn1 = *(const f32x4*)(xr + gwn * 256 + 4);
                }
                acc[i][0] += A1 * (pm0 + pc0 + pn0);
                acc[i][1] += A1 * (pm1 + pc1 + pn1);
                if (top) {   // tap k=0 extra weight on x[h-1][w-1]
                    acc[i][0] += A0D * pm0;
                    acc[i][1] += A0D * pm1;
                }
                pm0 = pc0; pm1 = pc1; pc0 = pn0; pc1 = pn1;
            }
        }

        // pack to bf16, write swizzled: byte ^= ((w&7)<<4)
#pragma unroll
        for (int i = 0; i < 2; ++i) {
            const int w = px0 + i;        // local row in [0,16)
            union { short8 v; unsigned short u[8]; } pk;
#pragma unroll
            for (int j = 0; j < 4; ++j) {
                pk.u[j]     = f2bf(acc[i][0][j]);
                pk.u[4 + j] = f2bf(acc[i][1][j]);
            }
            unsigned baddr = ((unsigned)w * 512u + (unsigned)c0 * 2u) ^ (((unsigned)(w & 7)) << 4);
            *reinterpret_cast<short8*>(ldsraw + baddr) = pk.v;
        }
    }
    __syncthreads();

    // ---------------- GEMM: wave wn -> 16px x 64e quarter ----------------
    const int wn   = t >> 6;          // 0..3
    const int lane = t & 63;
    const int lrow = lane & 15;
    const int lkg  = lane >> 4;       // 0..3

    f32x4 acc2[4];
    {
        const f32x4 z = {0.f, 0.f, 0.f, 0.f};
#pragma unroll
        for (int ni = 0; ni < 4; ++ni) acc2[ni] = z;

        const unsigned abase = (unsigned)lrow * 512u;
        const unsigned aswz  = ((unsigned)(lrow & 7)) << 4;
        const unsigned short* wv = Wm + (wn << 14) + (lane << 3);

#pragma unroll
        for (int kk = 0; kk < 8; ++kk) {
            const unsigned abyte = (abase + (unsigned)(kk * 64 + lkg * 16)) ^ aswz;
            short8 a = *reinterpret_cast<const short8*>(ldsraw + abyte);
            const unsigned short* wk = wv + (kk << 11);
#pragma unroll
            for (int ni = 0; ni < 4; ++ni) {
                short8 bf = *reinterpret_cast<const short8*>(wk + (ni << 9));
                acc2[ni] = __builtin_amdgcn_mfma_f32_16x16x32_bf16(bf, a, acc2[ni], 0, 0, 0);
            }
        }
    }
    __syncthreads();   // all waves done reading bf16 y-tile

    // ---------------- epilogue: LDS f32 transpose -> full-line stores ----------
    // D layout (verified): lane holds e = wn*64+ni*16+lkg*4+(0..3) for px = lrow.
#pragma unroll
    for (int ni = 0; ni < 4; ++ni) {
        unsigned baddr = ((unsigned)lrow * 1024u
                          + (unsigned)((wn * 64 + ni * 16 + lkg * 4) * 4))
                         ^ (((unsigned)(lrow & 7)) << 4);
        *reinterpret_cast<f32x4*>(ldsraw + baddr) = acc2[ni];
    }
    __syncthreads();

    // wave wn writes rows {wn, 4+wn, 8+wn, 12+wn}; each store = 1KB contiguous.
    const f32x4 bias = *reinterpret_cast<const f32x4*>(proj_b + lane * 4);
    const size_t pxbase = (size_t)idx * 16;
#pragma unroll
    for (int j = 0; j < 4; ++j) {
        const int row = j * 4 + wn;
        unsigned baddr = ((unsigned)row * 1024u + (unsigned)lane * 16u)
                         ^ (((unsigned)(row & 7)) << 4);
        f32x4 v = *reinterpret_cast<const f32x4*>(ldsraw + baddr) + bias;
        __builtin_nontemporal_store(v, reinterpret_cast<f32x4*>(out + (pxbase + row) * 256 + lane * 4));
    }
}

extern "C" void kernel_launch(void* const* d_in, const int* in_sizes, int n_in,
                              void* d_out, int out_size, void* d_ws, size_t ws_size,
                              hipStream_t stream) {
    const float* x      = (const float*)d_in[0];
    const float* v_w    = (const float*)d_in[1];
    const float* proj_w = (const float*)d_in[2];
    const float* proj_b = (const float*)d_in[3];
    float* out = (float*)d_out;
    unsigned short* Wm = (unsigned short*)d_ws;   // 65536 bf16 = 128 KB, swizzled

    wmat_kernel<<<256, 1024, 0, stream>>>(v_w, proj_w, Wm);
    fused_kernel<<<2048, 256, 0, stream>>>(x, Wm, proj_b, out);
}

// Round 9
// 27.823 us; speedup vs baseline: 2.8947x; 1.0725x over previous
//
#include <hip/hip_runtime.h>

typedef __attribute__((ext_vector_type(8))) short short8;
typedef __attribute__((ext_vector_type(4))) float f32x4;

__device__ __forceinline__ unsigned short f2bf(float f) {
    union { float f; unsigned int u; } v; v.f = f;
    unsigned int u = v.u;
    unsigned int r = u + 0x7FFFu + ((u >> 16) & 1u);
    return (unsigned short)(r >> 16);
}

// Kernel A (unchanged, R6/R8-verified): W = proj_w @ v_w, bf16, PRE-SWIZZLED:
// W[e][c], e=(wn*64+ni*16+lrow), c=(kk*32+lkg*8+c8), lane=lkg*16+lrow
// -> idx = (((wn*8+kk)*4+ni)*64 + lane)*8 + c8.
__global__ __launch_bounds__(1024) void wmat_kernel(
    const float* __restrict__ v_w, const float* __restrict__ proj_w,
    unsigned short* __restrict__ Wm)
{
    __shared__ float red[4][256];
    const int e  = blockIdx.x;
    const int c  = threadIdx.x & 255;
    const int dq = threadIdx.x >> 8;   // 0..3

    const float* pw = proj_w + e * 256 + dq * 64;   // wave-uniform -> s_loads
    const float* vv = v_w + (dq * 64) * 256 + c;

    float acc = 0.f;
#pragma unroll 8
    for (int d = 0; d < 64; ++d)
        acc = fmaf(pw[d], vv[d * 256], acc);

    red[dq][c] = acc;
    __syncthreads();
    if (threadIdx.x < 256) {
        float s = red[0][c] + red[1][c] + red[2][c] + red[3][c];
        const int wn = e >> 6, ni = (e >> 4) & 3, lrow = e & 15;
        const int kk = c >> 5, lkg = (c >> 3) & 3, c8 = c & 7;
        const int lane = lkg * 16 + lrow;
        const int idxo = ((((wn * 8 + kk) * 4 + ni) * 64 + lane) * 8) + c8;
        Wm[idxo] = f2bf(s);
    }
}

// Kernel B: one block per 32-px half-row, 1024 blocks x 512 threads (8 waves).
// launch_bounds(512,8) -> 4 blocks/CU = 32 waves/CU, VGPR<=64, LDS 32KB.
// Phase 1: blur -> bf16 ybuf (16KB, XOR-swizzled).
// Phase 2: k-loop, 8 chunks of K=32: stage 16KB W-chunk into wbuf ONCE per
//          block via global_load_lds (Wm traffic 128KB/block = 134MB total,
//          half of R8's 268MB), then conflict-free ds_read_b128 B-frags.
// Phase 3: f32 LDS transpose (reuses all 32KB) -> full-line 1KB row stores.
__global__ __launch_bounds__(512, 8) void fused_kernel(
    const float* __restrict__ x, const unsigned short* __restrict__ Wm,
    const float* __restrict__ proj_b, float* __restrict__ out)
{
    const int idx   = ((blockIdx.x & 7) << 7) | (blockIdx.x >> 3);  // 1024=8*128, bijective
    const int b     = idx >> 7;
    const int h     = (idx >> 1) & 63;
    const int wbase = (idx & 1) * 32;
    const int t     = threadIdx.x;

    __shared__ char lds[32768];   // [0,16K) ybuf bf16 | [16K,32K) wbuf bf16 | f32 tile reuses all

    const float A1  = (float)(1.0 / 10.71828182845904523536);                 // 1/(e+8)
    const float A0D = (float)(2.71828182845904523536 / 10.71828182845904523536) - A1; // A0-A1

    // ---------------- blur: 16 strips(2px) x 32 chunks(8ch) = 512 ----------------
    {
        const int strip = t >> 5;         // 0..15
        const int c0    = (t & 31) * 8;   // 8-channel chunk
        const int px0   = strip * 2;      // local pixel in [0,32)
        const int gw0   = wbase + px0;    // global pixel column

        const f32x4 z = {0.f, 0.f, 0.f, 0.f};
        f32x4 acc[2][2];
#pragma unroll
        for (int i = 0; i < 2; ++i) { acc[i][0] = z; acc[i][1] = z; }

        for (int r = h - 1; r <= h + 1; ++r) {
            if (r < 0 || r >= 64) continue;
            const bool top = (r == h - 1);
            const float* xr = x + (((size_t)b * 64 + r) * 64) * 256 + c0;

            f32x4 pm0, pm1, pc0, pc1;
            if (gw0 == 0) { pm0 = z; pm1 = z; }
            else {
                pm0 = *(const f32x4*)(xr + (gw0 - 1) * 256);
                pm1 = *(const f32x4*)(xr + (gw0 - 1) * 256 + 4);
            }
            pc0 = *(const f32x4*)(xr + gw0 * 256);
            pc1 = *(const f32x4*)(xr + gw0 * 256 + 4);

#pragma unroll
            for (int i = 0; i < 2; ++i) {
                const int gwn = gw0 + i + 1;
                f32x4 pn0 = z, pn1 = z;
                if (gwn < 64) {
                    pn0 = *(const f32x4*)(xr + gwn * 256);
                    pn1 = *(const f32x4*)(xr + gwn * 256 + 4);
                }
                acc[i][0] += A1 * (pm0 + pc0 + pn0);
                acc[i][1] += A1 * (pm1 + pc1 + pn1);
                if (top) {   // tap k=0 extra weight on x[h-1][w-1]
                    acc[i][0] += A0D * pm0;
                    acc[i][1] += A0D * pm1;
                }
                pm0 = pc0; pm1 = pc1; pc0 = pn0; pc1 = pn1;
            }
        }

        // pack to bf16, write swizzled: byte ^= ((w&7)<<4)
#pragma unroll
        for (int i = 0; i < 2; ++i) {
            const int w = px0 + i;        // local row in [0,32)
            union { short8 v; unsigned short u[8]; } pk;
#pragma unroll
            for (int j = 0; j < 4; ++j) {
                pk.u[j]     = f2bf(acc[i][0][j]);
                pk.u[4 + j] = f2bf(acc[i][1][j]);
            }
            unsigned baddr = ((unsigned)w * 512u + (unsigned)c0 * 2u) ^ (((unsigned)(w & 7)) << 4);
            *reinterpret_cast<short8*>(lds + baddr) = pk.v;
        }
    }

    // ---------------- GEMM: 8 waves = 2(mi) x 4(wn), k staged in LDS ----------------
    const int w    = t >> 6;          // wave 0..7
    const int lane = t & 63;
    const int mi   = w >> 2;          // 0..1  -> 16-px half
    const int wn   = w & 3;           // 0..3  -> 64-e quarter
    const int lrow = lane & 15;
    const int lkg  = lane >> 4;       // 0..3
    const int row  = mi * 16 + lrow;  // local pixel this lane produces

    f32x4 acc2[4];
    {
        const f32x4 z = {0.f, 0.f, 0.f, 0.f};
#pragma unroll
        for (int ni = 0; ni < 4; ++ni) acc2[ni] = z;
    }

    const unsigned abase = (unsigned)row * 512u;
    const unsigned aswz  = ((unsigned)(row & 7)) << 4;

    for (int kk = 0; kk < 8; ++kk) {
        __syncthreads();   // kk=0: blur done; kk>0: prev chunk's B-reads done
        // stage W chunk kk: wave w copies groups g = 2w, 2w+1 (1KB each, coalesced)
#pragma unroll
        for (int q = 0; q < 2; ++q) {
            const int g = w * 2 + q;                       // g = wn_s*4 + ni_s
            const unsigned short* src =
                Wm + ((((size_t)(g >> 2) * 8 + kk) * 4 + (g & 3)) * 64 + lane) * 8;
            __builtin_amdgcn_global_load_lds(src, (lds + 16384 + g * 1024), 16, 0, 0);
        }
        __syncthreads();   // staging complete (vmcnt drained before barrier)

        const unsigned abyte = (abase + (unsigned)(kk * 64 + lkg * 16)) ^ aswz;
        short8 a = *reinterpret_cast<const short8*>(lds + abyte);
#pragma unroll
        for (int ni = 0; ni < 4; ++ni) {
            short8 bf = *reinterpret_cast<const short8*>(
                lds + 16384 + ((wn * 4 + ni) * 64 + lane) * 16);
            acc2[ni] = __builtin_amdgcn_mfma_f32_16x16x32_bf16(bf, a, acc2[ni], 0, 0, 0);
        }
    }
    __syncthreads();   // all B/A reads done; lds becomes f32 out-tile [32][256]

    // ---------------- epilogue: transpose via f32 LDS, full-line stores ---------
    // D layout (R3/R6/R8-verified): lane holds e = wn*64+ni*16+lkg*4+(0..3), px=row.
#pragma unroll
    for (int ni = 0; ni < 4; ++ni) {
        const unsigned e0 = (unsigned)(wn * 64 + ni * 16 + lkg * 4);
        unsigned baddr = ((unsigned)row * 1024u + e0 * 4u) ^ (((unsigned)(row & 7)) << 4);
        *reinterpret_cast<f32x4*>(lds + baddr) = acc2[ni];
    }
    __syncthreads();

    const f32x4 bias = *reinterpret_cast<const f32x4*>(proj_b + lane * 4);
    const size_t pxbase = (size_t)idx * 32;
#pragma unroll
    for (int j = 0; j < 4; ++j) {
        const int r = j * 8 + w;    // 8 waves x 4 rows = 32 rows
        unsigned baddr = ((unsigned)r * 1024u + (unsigned)lane * 16u)
                         ^ (((unsigned)(r & 7)) << 4);
        f32x4 v = *reinterpret_cast<const f32x4*>(lds + baddr) + bias;
        __builtin_nontemporal_store(v, reinterpret_cast<f32x4*>(out + (pxbase + r) * 256 + lane * 4));
    }
}

extern "C" void kernel_launch(void* const* d_in, const int* in_sizes, int n_in,
                              void* d_out, int out_size, void* d_ws, size_t ws_size,
                              hipStream_t stream) {
    const float* x      = (const float*)d_in[0];
    const float* v_w    = (const float*)d_in[1];
    const float* proj_w = (const float*)d_in[2];
    const float* proj_b = (const float*)d_in[3];
    float* out = (float*)d_out;
    unsigned short* Wm = (unsigned short*)d_ws;   // 65536 bf16 = 128 KB, swizzled

    wmat_kernel<<<256, 1024, 0, stream>>>(v_w, proj_w, Wm);
    fused_kernel<<<1024, 512, 0, stream>>>(x, Wm, proj_b, out);
}